// Round 1
// baseline (1370.211 us; speedup 1.0000x reference)
//
#include <hip/hip_runtime.h>
#include <hip/hip_bf16.h>
#include <math.h>

// Segmented max over sorted batch indices.
// feats: [N, 64] fp32 row-major; batch_idx: [N] int32 sorted; out: [64, 64] fp32.
// Memory-bound: ~1.09 GB must stream from HBM -> floor ~173 us @ 6.3 TB/s.

#define D 64
#define BLOCK 256
#define GRID 2048

// Exact float atomic max via sign-split integer atomics.
// Identity is -inf (0xFF800000). No NaNs in this problem.
__device__ __forceinline__ void atomic_max_float(float* addr, float v) {
    if (v >= 0.0f) {
        atomicMax((int*)addr, __float_as_int(v));
    } else {
        atomicMin((unsigned int*)addr, __float_as_uint(v));
    }
}

__global__ void init_out_kernel(float* out, int n) {
    int i = blockIdx.x * blockDim.x + threadIdx.x;
    if (i < n) out[i] = -INFINITY;  // segment_max identity
}

__global__ void __launch_bounds__(BLOCK) seg_max_kernel(
        const float4* __restrict__ feats4,   // [N, 16] float4 view of [N, 64] floats
        const int* __restrict__ bidx,        // [N]
        float* __restrict__ out,             // [B, 64]
        int rows_per_block, int N) {
    const int tid    = threadIdx.x;
    const int lane   = tid & 63;
    const int wave   = tid >> 6;       // 0..3
    const int rgroup = lane >> 4;      // which of 4 rows this quad of lanes handles
    const int fquad  = lane & 15;      // which float4 within the 64-float row

    const long long block_start = (long long)blockIdx.x * rows_per_block;
    long long block_end = block_start + rows_per_block;
    if (block_end > N) block_end = N;

    // This thread walks rows: block_start + wave*4 + rgroup, stride 16.
    long long r = block_start + (long long)(wave * 4 + rgroup);

    int cur_seg = -1;
    float4 m = make_float4(-INFINITY, -INFINITY, -INFINITY, -INFINITY);

    for (; r < block_end; r += 16) {
        int seg  = bidx[r];                      // 16 lanes share this (cached)
        float4 v = feats4[r * 16 + fquad];       // wave: 1KB contiguous dwordx4
        if (seg != cur_seg) {
            // sorted indices -> this is rare (<= ~1 boundary per block chunk)
            if (cur_seg >= 0) {
                float* o = out + cur_seg * D + fquad * 4;
                atomic_max_float(o + 0, m.x);
                atomic_max_float(o + 1, m.y);
                atomic_max_float(o + 2, m.z);
                atomic_max_float(o + 3, m.w);
            }
            cur_seg = seg;
            m = v;
        } else {
            m.x = fmaxf(m.x, v.x);
            m.y = fmaxf(m.y, v.y);
            m.z = fmaxf(m.z, v.z);
            m.w = fmaxf(m.w, v.w);
        }
    }
    if (cur_seg >= 0) {
        float* o = out + cur_seg * D + fquad * 4;
        atomic_max_float(o + 0, m.x);
        atomic_max_float(o + 1, m.y);
        atomic_max_float(o + 2, m.z);
        atomic_max_float(o + 3, m.w);
    }
}

extern "C" void kernel_launch(void* const* d_in, const int* in_sizes, int n_in,
                              void* d_out, int out_size, void* d_ws, size_t ws_size,
                              hipStream_t stream) {
    const float* feats = (const float*)d_in[0];
    const int*   bidx  = (const int*)d_in[1];
    float*       out   = (float*)d_out;

    const int N = in_sizes[1];   // number of rows (batch_idx element count)

    // 1) init output to -inf (harness re-poisons d_out to 0xAA before each call)
    init_out_kernel<<<(out_size + BLOCK - 1) / BLOCK, BLOCK, 0, stream>>>(out, out_size);

    // 2) segmented max; contiguous chunk per block, multiple of 16 rows
    int rpb = ((N + GRID * 16 - 1) / (GRID * 16)) * 16;
    seg_max_kernel<<<GRID, BLOCK, 0, stream>>>(
        (const float4*)feats, bidx, out, rpb, N);
}